// Round 6
// baseline (1055.690 us; speedup 1.0000x reference)
//
#include <hip/hip_runtime.h>
#include <math.h>

#define BNUM 32
#define NBIN 2048
#define CAP  2048
#define N0 76800
#define N1 19200
#define N2 4800
#define GRID 512

// device-resident scratch (VRAM)
__device__ __align__(16) int   g_hist[96*NBIN];
__device__ int   g_candcnt[96];
__device__ float g_acc[480];
__device__ int   g_binr[192];
__device__ float g_part[96*100*5];
__device__ float g_cand[96*CAP];
__device__ float g_parts2[96*100*2];
__device__ float g_gl[288];

// grid barrier state: count returns to 0 after each barrier; gen is monotonic
// across calls/replays (no per-call reset needed -> graph-capture safe).
__device__ int      g_bar_count = 0;
__device__ unsigned g_bar_gen   = 0;

__device__ __forceinline__ void gridbar(){
  __syncthreads();
  if (threadIdx.x == 0){
    __threadfence();  // make this block's writes visible device-wide
    unsigned gen = __hip_atomic_load(&g_bar_gen, __ATOMIC_RELAXED, __HIP_MEMORY_SCOPE_AGENT);
    int prev = __hip_atomic_fetch_add(&g_bar_count, 1, __ATOMIC_ACQ_REL, __HIP_MEMORY_SCOPE_AGENT);
    if (prev == GRID-1){
      __hip_atomic_store(&g_bar_count, 0, __ATOMIC_RELAXED, __HIP_MEMORY_SCOPE_AGENT);
      __hip_atomic_store(&g_bar_gen, gen+1, __ATOMIC_RELEASE, __HIP_MEMORY_SCOPE_AGENT);
    } else {
      while (__hip_atomic_load(&g_bar_gen, __ATOMIC_ACQUIRE, __HIP_MEMORY_SCOPE_AGENT) == gen)
        __builtin_amdgcn_s_sleep(8);
    }
    __threadfence();
  }
  __syncthreads();
}

__device__ __forceinline__ float wred(float v){
  #pragma unroll
  for (int off=32; off; off>>=1) v += __shfl_down(v, off, 64);
  return v;
}

__global__ __launch_bounds__(256, 2) void fused(
    const float* __restrict__ p0, const float* __restrict__ p1, const float* __restrict__ p2,
    const float* __restrict__ boxes, const int* __restrict__ labels, float* __restrict__ out)
{
  const int t = threadIdx.x;
  const int blk = blockIdx.x;
  const int lane = t & 63, wv = t >> 6;

  __shared__ float sraw[64];
  __shared__ float scor[16][5];
  __shared__ int   slab[16];
  __shared__ int   shist[NBIN];
  __shared__ float sc[CAP];
  __shared__ int   sa[256], sb[256];
  __shared__ float red[5][4];
  __shared__ int   s_k;
  __shared__ float s_thr;

  // ---------------- P0: zero hist + candcnt ----------------
  for (int i = blk*256 + t; i < 96*NBIN; i += GRID*256) g_hist[i] = 0;
  if (blk == 0 && t < 96) g_candcnt[t] = 0;
  gridbar();

  // ---------------- P1: scan, grid-stride over 4224 tiles ----------------
  for (int vt = blk; vt < 4224; vt += GRID){
    const int b  = vt / 132;
    const int bx = vt - b*132;
    int s, lb, W, HW; const float* __restrict__ pred;
    if (bx < 100)      { s=0; lb=bx;     W=160; HW=25600; pred=p0; }
    else if (bx < 125) { s=1; lb=bx-100; W=80;  HW=6400;  pred=p1; }
    else               { s=2; lb=bx-125; W=40;  HW=1600;  pred=p2; }
    const int g = s*BNUM + b;

    #pragma unroll
    for (int j=0;j<NBIN/256;j++) shist[t + j*256] = 0;
    if (t < 64) sraw[t] = boxes[b*64 + t];
    else if (t < 80) slab[t-64] = labels[b*16 + t - 64];
    __syncthreads();
    if (t < 16){
      float bcx=sraw[4*t], bcy=sraw[4*t+1], bw=sraw[4*t+2], bh=sraw[4*t+3];
      float x0=bcx-bw*0.5f, y0=bcy-bh*0.5f, x1=bcx+bw*0.5f, y1=bcy+bh*0.5f;
      scor[t][0]=x0; scor[t][1]=y0; scor[t][2]=x1; scor[t][3]=y1;
      scor[t][4]=(x1-x0)*(y1-y0);
    }
    __syncthreads();

    const int pix = lb*256 + t;
    float f_pos=0.f, f_neg=0.f, f_obj=0.f, f_ce=0.f, f_sl1=0.f;

    if (pix < HW){
      const int h = pix / W;
      const int w = pix - h*W;
      const float fw = (float)W;
      const float cx = ((float)w + 0.5f)/fw;
      const float cy = ((float)h + 0.5f)/fw;
      const float* pb = pred + (size_t)b*24*HW;

      #pragma unroll
      for (int a=0;a<3;a++){
        const float sz = (a==0)?0.08f:((a==1)?0.16f:0.28f);
        const float hs = sz*0.5f;
        const float ax0=cx-hs, ay0=cy-hs, ax1=cx+hs, ay1=cy+hs;
        const float areaA=(ax1-ax0)*(ay1-ay0);
        float best=-1.f; int midx=0;
        #pragma unroll
        for (int m=0;m<16;m++){
          float iw=fminf(ax1,scor[m][2])-fmaxf(ax0,scor[m][0]);
          float ih=fminf(ay1,scor[m][3])-fmaxf(ay0,scor[m][1]);
          iw=fmaxf(iw,0.f); ih=fmaxf(ih,0.f);
          float inter=iw*ih;
          float iou=inter/(areaA+scor[m][4]-inter+1e-9f);
          if (iou>best){best=iou; midx=m;}
        }
        const bool pos = best>=0.5f;
        const bool neg = best<0.4f;
        const float obj = pb[(a*8+4)*HW + pix];
        const float sp = log1pf(expf(-fabsf(obj)));
        const float obj_all = fmaxf(obj,0.f) - (pos?obj:0.f) + sp;
        if (neg){
          f_neg += 1.f;
          atomicAdd(&shist[__float_as_uint(obj_all)>>20], 1);
        } else if (pos){
          f_pos += 1.f; f_obj += obj_all;
          float c0=pb[(a*8+5)*HW+pix], c1=pb[(a*8+6)*HW+pix], c2=pb[(a*8+7)*HW+pix];
          float mx=fmaxf(c0,fmaxf(c1,c2));
          float lse=mx+logf(expf(c0-mx)+expf(c1-mx)+expf(c2-mx));
          int ct=slab[midx]-1; ct = ct<0?0:(ct>2?2:ct);
          float csel=(ct==0)?c0:((ct==1)?c1:c2);
          f_ce += lse-csel;
          float mcx=sraw[4*midx],mcy=sraw[4*midx+1],mw=sraw[4*midx+2],mh=sraw[4*midx+3];
          float t0=(mcx-cx)/sz, t1=(mcy-cy)/sz, t2=logf(mw/sz), t3=logf(mh/sz);
          float l0=pb[(a*8+0)*HW+pix], l1=pb[(a*8+1)*HW+pix];
          float l2=pb[(a*8+2)*HW+pix], l3=pb[(a*8+3)*HW+pix];
          float d, ssm=0.f;
          d=fabsf(l0-t0); ssm += (d<1.f)?(0.5f*d*d):(d-0.5f);
          d=fabsf(l1-t1); ssm += (d<1.f)?(0.5f*d*d):(d-0.5f);
          d=fabsf(l2-t2); ssm += (d<1.f)?(0.5f*d*d):(d-0.5f);
          d=fabsf(l3-t3); ssm += (d<1.f)?(0.5f*d*d):(d-0.5f);
          f_sl1 += ssm;
        }
      }
    }
    __syncthreads();
    #pragma unroll
    for (int j=0;j<NBIN/256;j++){
      int bin = t + j*256;
      int c = shist[bin];
      if (c) atomicAdd(&g_hist[g*NBIN + bin], c);
    }
    float vals[5] = {f_pos, f_neg, f_obj, f_ce, f_sl1};
    #pragma unroll
    for (int q=0;q<5;q++){
      float r = wred(vals[q]);
      if (lane==0) red[q][wv] = r;
    }
    __syncthreads();
    if (t==0){
      float* pg = g_part + (size_t)(g*100 + lb)*5;
      #pragma unroll
      for (int q=0;q<5;q++) pg[q] = red[q][0]+red[q][1]+red[q][2]+red[q][3];
    }
    __syncthreads();
  }
  gridbar();

  // ---------------- P2: findbin (blocks 0..95) ----------------
  if (blk < 96){
    const int g = blk;
    const int s = g >> 5;
    const int nb = (s==0)?100:((s==1)?25:7);

    const int4* h4 = (const int4*)(g_hist + g*NBIN);
    int4 v0 = h4[t*2+0], v1 = h4[t*2+1];
    int lv[8] = {v0.x,v0.y,v0.z,v0.w, v1.x,v1.y,v1.z,v1.w};
    int sum = 0;
    #pragma unroll
    for (int j=0;j<8;j++) sum += lv[j];

    float pv[5] = {0.f,0.f,0.f,0.f,0.f};
    if (t < nb){
      const float* pg = g_part + (size_t)(g*100 + t)*5;
      #pragma unroll
      for (int q=0;q<5;q++) pv[q] = pg[q];
    }
    #pragma unroll
    for (int q=0;q<5;q++){
      float r = wred(pv[q]);
      if (lane==0) red[q][wv] = r;
    }
    __syncthreads();
    if (t==0){
      float tot[5];
      #pragma unroll
      for (int q=0;q<5;q++){
        tot[q] = red[q][0]+red[q][1]+red[q][2]+red[q][3];
        g_acc[g*5+q] = tot[q];
      }
      const int npos = (int)(tot[0]+0.5f), avail = (int)(tot[1]+0.5f);
      int k = (npos==0) ? (avail<100?avail:100) : (3*npos<avail?3*npos:avail);
      s_k = k;
      if (k<=0){ g_binr[g*2]=NBIN; g_binr[g*2+1]=0; }
    }
    __syncthreads();
    const int k = s_k;

    sa[t] = sum; __syncthreads();
    int* src = sa; int* dst = sb;
    #pragma unroll
    for (int st=1; st<256; st<<=1){
      int v = src[t] + ((t+st<256)? src[t+st] : 0);
      dst[t] = v; __syncthreads();
      int* tmp = src; src = dst; dst = tmp;
    }
    if (k>0){
      int above = (t<255) ? src[t+1] : 0;
      if (above < k && above + sum >= k){
        int cum = above;
        #pragma unroll
        for (int j=7;j>=0;j--){
          int c = lv[j];
          if (cum + c >= k){ g_binr[g*2] = t*8 + j; g_binr[g*2+1] = k - cum; break; }
          cum += c;
        }
      }
    }
  }
  gridbar();

  // ---------------- P3: re-scan negatives, grid-stride over 4224 tiles ----------------
  for (int vt = blk; vt < 4224; vt += GRID){
    const int b  = vt / 132;
    const int bx = vt - b*132;
    int s, lb, W, HW; const float* __restrict__ pred;
    if (bx < 100)      { s=0; lb=bx;     W=160; HW=25600; pred=p0; }
    else if (bx < 125) { s=1; lb=bx-100; W=80;  HW=6400;  pred=p1; }
    else               { s=2; lb=bx-125; W=40;  HW=1600;  pred=p2; }
    const int g = s*BNUM + b;
    const int pbin = g_binr[g*2];

    if (t < 64) sraw[t] = boxes[b*64 + t];
    __syncthreads();
    if (t < 16){
      float bcx=sraw[4*t], bcy=sraw[4*t+1], bw=sraw[4*t+2], bh=sraw[4*t+3];
      float x0=bcx-bw*0.5f, y0=bcy-bh*0.5f, x1=bcx+bw*0.5f, y1=bcy+bh*0.5f;
      scor[t][0]=x0; scor[t][1]=y0; scor[t][2]=x1; scor[t][3]=y1;
      scor[t][4]=(x1-x0)*(y1-y0);
    }
    __syncthreads();

    const int pix = lb*256 + t;
    float sum=0.f, cnt=0.f;
    if (pix < HW){
      const int h = pix / W;
      const int w = pix - h*W;
      const float fw = (float)W;
      const float cx = ((float)w + 0.5f)/fw;
      const float cy = ((float)h + 0.5f)/fw;
      const float* pb = pred + (size_t)b*24*HW;

      #pragma unroll
      for (int a=0;a<3;a++){
        const float sz = (a==0)?0.08f:((a==1)?0.16f:0.28f);
        const float hs = sz*0.5f;
        const float ax0=cx-hs, ay0=cy-hs, ax1=cx+hs, ay1=cy+hs;
        const float areaA=(ax1-ax0)*(ay1-ay0);
        float best=-1.f;
        #pragma unroll
        for (int m=0;m<16;m++){
          float iw=fminf(ax1,scor[m][2])-fmaxf(ax0,scor[m][0]);
          float ih=fminf(ay1,scor[m][3])-fmaxf(ay0,scor[m][1]);
          iw=fmaxf(iw,0.f); ih=fmaxf(ih,0.f);
          float inter=iw*ih;
          float iou=inter/(areaA+scor[m][4]-inter+1e-9f);
          if (iou>best) best=iou;
        }
        if (best < 0.4f){
          const float obj = pb[(a*8+4)*HW + pix];
          const float v = fmaxf(obj,0.f) + log1pf(expf(-fabsf(obj)));
          const int vb = (int)(__float_as_uint(v)>>20);
          if (vb > pbin){ sum += v; cnt += 1.f; }
          else if (vb == pbin){
            int idx = atomicAdd(&g_candcnt[g], 1);
            if (idx < CAP) g_cand[g*CAP + idx] = v;
          }
        }
      }
    }
    float r0 = wred(sum), r1 = wred(cnt);
    if (lane==0){ red[0][wv]=r0; red[1][wv]=r1; }
    __syncthreads();
    if (t==0){
      float* pg = g_parts2 + (size_t)(g*100 + lb)*2;
      pg[0] = red[0][0]+red[0][1]+red[0][2]+red[0][3];
      pg[1] = red[1][0]+red[1][1]+red[1][2]+red[1][3];
    }
    __syncthreads();
  }
  gridbar();

  // ---------------- P4: rank (blocks 0..95) ----------------
  if (blk < 96){
    const int g = blk;
    const int s = g >> 5;
    const int nb2 = (s==0)?100:((s==1)?25:7);

    float asum=0.f, acnt=0.f;
    if (t < nb2){
      const float* pg = g_parts2 + (size_t)(g*100 + t)*2;
      asum = pg[0]; acnt = pg[1];
    }
    const float nposf = g_acc[g*5+0], availf = g_acc[g*5+1];
    const int npos = (int)(nposf+0.5f), avail = (int)(availf+0.5f);
    const int k = (npos==0) ? (avail<100?avail:100) : (3*npos<avail?3*npos:avail);
    float selS=0.f, selC=0.f;
    if (k > 0){
      const int m = min(g_candcnt[g], CAP);
      const int r = g_binr[g*2+1];
      if (t==0) s_thr = INFINITY;
      for (int i=t; i<m; i+=256) sc[i] = g_cand[g*CAP + i];
      __syncthreads();
      for (int i=t; i<m; i+=256){
        float v = sc[i]; int gt=0, ge=0;
        for (int j=0;j<m;j++){ float w2 = sc[j]; gt += (w2>v)?1:0; ge += (w2>=v)?1:0; }
        if (gt < r && ge >= r) s_thr = v;
      }
      __syncthreads();
      const float thr = s_thr;
      for (int i=t; i<m; i+=256){ float v = sc[i]; if (v >= thr){ selS += v; selC += 1.f; } }
    }
    float r0 = wred(asum + selS), r1 = wred(acnt + selC);
    if (lane==0){ red[0][wv]=r0; red[1][wv]=r1; }
    __syncthreads();
    if (t==0){
      float ss = red[0][0]+red[0][1]+red[0][2]+red[0][3];
      float ns = red[1][0]+red[1][1]+red[1][2]+red[1][3];
      float totS = ss + g_acc[g*5+2];
      float totC = ns + nposf;
      g_gl[g*3+0] = (totC > 0.f) ? totS/totC : 0.f;
      g_gl[g*3+1] = (npos > 0) ? g_acc[g*5+3]/nposf : 0.f;
      g_gl[g*3+2] = (npos > 0) ? g_acc[g*5+4]/(nposf*4.f) : 0.f;
    }
  }
  gridbar();

  // ---------------- P5: final (block 0) ----------------
  if (blk == 0){
    float lo=0.f, lc=0.f, ll=0.f;
    if (t < 96){ lo=g_gl[t*3]; lc=g_gl[t*3+1]; ll=g_gl[t*3+2]; }
    float r0=wred(lo), r1=wred(lc), r2=wred(ll);
    if (lane==0){ red[0][wv]=r0; red[1][wv]=r1; red[2][wv]=r2; }
    __syncthreads();
    if (t==0){
      float a = (red[0][0]+red[0][1]+red[0][2]+red[0][3])*(1.f/32.f);
      float b = (red[1][0]+red[1][1]+red[1][2]+red[1][3])*(1.f/32.f);
      float c = (red[2][0]+red[2][1]+red[2][2]+red[2][3])*(1.f/32.f);
      out[0]=a; out[1]=b; out[2]=c; out[3]=a+b+c;
    }
  }
}

extern "C" void kernel_launch(void* const* d_in, const int* in_sizes, int n_in,
                              void* d_out, int out_size, void* d_ws, size_t ws_size,
                              hipStream_t stream)
{
  const float* p0 = (const float*)d_in[0];
  const float* p1 = (const float*)d_in[1];
  const float* p2 = (const float*)d_in[2];
  const float* boxes  = (const float*)d_in[6];
  const int*   labels = (const int*)d_in[7];
  float* out = (float*)d_out;

  fused<<<dim3(GRID), 256, 0, stream>>>(p0, p1, p2, boxes, labels, out);
}